// Round 5
// baseline (225.241 us; speedup 1.0000x reference)
//
#include <hip/hip_runtime.h>
#include <math.h>

#define N_TOK   16384
#define EDIM    64
#define NE      4096
#define CHUNK   128                      /* codes staged per LDS chunk */
#define TPB     256
#define TOKPT   2                        /* tokens per thread          */
#define ZQ_OFF  1
#define IDX_OFF (1 + N_TOK * EDIM)       /* 1048577 */
#define PERP_OFF (IDX_OFF + N_TOK)       /* 1064961 */

typedef unsigned long long u64;
typedef float v2f __attribute__((ext_vector_type(2)));
typedef float v4f __attribute__((ext_vector_type(4)));

// ---------------------------------------------------------------------------
// Kernel B (fused with norms + zeroing): distances + per-slice argmin.
// One thread = TWO tokens, stored INTERLEAVED as zp[j] = (z0[j], z1[j]) in 64
// VGPR pairs. Codebook chunk (128 codes, 32 KB) staged in LDS, read as
// wave-uniform broadcast float4s. Inner product uses v_pk_fma_f32: one packed
// FMA per dim covers both tokens; op_sel broadcasts the code element
// (src1.lo or src1.hi) to both halves. Each packed lane is the SAME
// sequential j-ascending IEEE-FMA chain as the passing rounds 1-3 ->
// bitwise-identical d -> np.argmin ties exact.
//   lo-broadcast: op_sel:[0,0,0] op_sel_hi:[1,0,1]  (src1.lo both halves)
//   hi-broadcast: op_sel:[0,1,0] op_sel_hi:[1,1,1]  (src1.hi both halves)
// d = fma(-2, dot, nz+ne[k]); argmin packed (d_bits<<32)|k, u64 min ==
// first-index tie-break (d>0 so float bits monotone).
// nz (own tokens) and ne (staged codes) are computed in-kernel with the exact
// numpy pairwise_sum replication (8 accs stride 8, contract off) used before.
// slice==0 blocks also zero hist/lossAcc (reduce runs after, stream-ordered).
// ---------------------------------------------------------------------------
__global__ __launch_bounds__(256, 2) void dist_argmin_kernel(
    const float* __restrict__ z, const float* __restrict__ cb,
    u64* __restrict__ part, int* __restrict__ hist,
    float* __restrict__ lossAcc, int csl) {
    __shared__ float se[CHUNK * EDIM];   // 32 KB
    __shared__ float sne[CHUNK];
    const int tid    = threadIdx.x;
    const int token0 = blockIdx.x * (TPB * TOKPT) + tid;   // tokens tid, tid+256
    const int token1 = token0 + TPB;
    const int slice  = blockIdx.y;

    if (slice == 0) {                    // grid.x*TPB = 8192 >= NE+1
        int gid = blockIdx.x * TPB + tid;
        if (gid < NE) hist[gid] = 0;
        if (gid == NE) lossAcc[0] = 0.0f;
    }

    // Load both tokens interleaved; compute nz with numpy pairwise replication.
    v2f zp[EDIM];
    {
        const v4f* zp0 = (const v4f*)(z + (size_t)token0 * EDIM);
        const v4f* zp1 = (const v4f*)(z + (size_t)token1 * EDIM);
#pragma unroll
        for (int q = 0; q < 16; ++q) {
            v4f a = zp0[q], b = zp1[q];
            zp[4 * q + 0].x = a.x; zp[4 * q + 0].y = b.x;
            zp[4 * q + 1].x = a.y; zp[4 * q + 1].y = b.y;
            zp[4 * q + 2].x = a.z; zp[4 * q + 2].y = b.z;
            zp[4 * q + 3].x = a.w; zp[4 * q + 3].y = b.w;
        }
    }
    float tnz0, tnz1;
    {
#pragma clang fp contract(off)
        float r0[8], r1[8];
#pragma unroll
        for (int j = 0; j < 8; ++j) {
            float v0 = zp[j].x, v1 = zp[j].y;
            r0[j] = v0 * v0; r1[j] = v1 * v1;
        }
#pragma unroll
        for (int b = 8; b < 64; b += 8) {
#pragma unroll
            for (int j = 0; j < 8; ++j) {
                float v0 = zp[b + j].x, v1 = zp[b + j].y;
                r0[j] = r0[j] + v0 * v0; r1[j] = r1[j] + v1 * v1;
            }
        }
        tnz0 = ((r0[0] + r0[1]) + (r0[2] + r0[3])) + ((r0[4] + r0[5]) + (r0[6] + r0[7]));
        tnz1 = ((r1[0] + r1[1]) + (r1[2] + r1[3])) + ((r1[4] + r1[5]) + (r1[6] + r1[7]));
    }

    u64 best0 = ~0ull, best1 = ~0ull;
    const int kend = slice * csl + csl;
#pragma unroll 1
    for (int kbase = slice * csl; kbase < kend; kbase += CHUNK) {
        {   // stage 128 codes -> LDS
            const v4f* src = (const v4f*)(cb + (size_t)kbase * EDIM);
            v4f* dst = (v4f*)se;
#pragma unroll
            for (int r = 0; r < (CHUNK * EDIM / 4) / TPB; ++r)
                dst[r * TPB + tid] = src[r * TPB + tid];
        }
        if (tid < CHUNK) {
#pragma clang fp contract(off)
            // ne for staged codes, numpy pairwise replication
            const v4f* cr = (const v4f*)(cb + (size_t)(kbase + tid) * EDIM);
            float r[8];
            {
                v4f c0 = cr[0], c1 = cr[1];
                r[0] = c0.x * c0.x; r[1] = c0.y * c0.y;
                r[2] = c0.z * c0.z; r[3] = c0.w * c0.w;
                r[4] = c1.x * c1.x; r[5] = c1.y * c1.y;
                r[6] = c1.z * c1.z; r[7] = c1.w * c1.w;
            }
#pragma unroll
            for (int b = 1; b < 8; ++b) {
                v4f a = cr[2 * b], d = cr[2 * b + 1];
                r[0] = r[0] + a.x * a.x; r[1] = r[1] + a.y * a.y;
                r[2] = r[2] + a.z * a.z; r[3] = r[3] + a.w * a.w;
                r[4] = r[4] + d.x * d.x; r[5] = r[5] + d.y * d.y;
                r[6] = r[6] + d.z * d.z; r[7] = r[7] + d.w * d.w;
            }
            sne[tid] = ((r[0] + r[1]) + (r[2] + r[3])) + ((r[4] + r[5]) + (r[6] + r[7]));
        }
        __syncthreads();

#pragma unroll 1
        for (int k = 0; k < CHUNK; k += 2) {
            const v4f* e0 = (const v4f*)(se + (size_t)(k + 0) * EDIM);
            const v4f* e1 = (const v4f*)(se + (size_t)(k + 1) * EDIM);
            v2f a0 = {0.f, 0.f}, a1 = {0.f, 0.f};
#pragma unroll
            for (int q = 0; q < 16; ++q) {
                v4f A = e0[q], B = e1[q];
                v2f Alo = __builtin_shufflevector(A, A, 0, 1);
                v2f Ahi = __builtin_shufflevector(A, A, 2, 3);
                v2f Blo = __builtin_shufflevector(B, B, 0, 1);
                v2f Bhi = __builtin_shufflevector(B, B, 2, 3);
                asm("v_pk_fma_f32 %0, %1, %2, %0 op_sel:[0,0,0] op_sel_hi:[1,0,1]"
                    : "+v"(a0) : "v"(zp[4 * q + 0]), "v"(Alo));
                asm("v_pk_fma_f32 %0, %1, %2, %0 op_sel:[0,1,0] op_sel_hi:[1,1,1]"
                    : "+v"(a0) : "v"(zp[4 * q + 1]), "v"(Alo));
                asm("v_pk_fma_f32 %0, %1, %2, %0 op_sel:[0,0,0] op_sel_hi:[1,0,1]"
                    : "+v"(a0) : "v"(zp[4 * q + 2]), "v"(Ahi));
                asm("v_pk_fma_f32 %0, %1, %2, %0 op_sel:[0,1,0] op_sel_hi:[1,1,1]"
                    : "+v"(a0) : "v"(zp[4 * q + 3]), "v"(Ahi));
                asm("v_pk_fma_f32 %0, %1, %2, %0 op_sel:[0,0,0] op_sel_hi:[1,0,1]"
                    : "+v"(a1) : "v"(zp[4 * q + 0]), "v"(Blo));
                asm("v_pk_fma_f32 %0, %1, %2, %0 op_sel:[0,1,0] op_sel_hi:[1,1,1]"
                    : "+v"(a1) : "v"(zp[4 * q + 1]), "v"(Blo));
                asm("v_pk_fma_f32 %0, %1, %2, %0 op_sel:[0,0,0] op_sel_hi:[1,0,1]"
                    : "+v"(a1) : "v"(zp[4 * q + 2]), "v"(Bhi));
                asm("v_pk_fma_f32 %0, %1, %2, %0 op_sel:[0,1,0] op_sel_hi:[1,1,1]"
                    : "+v"(a1) : "v"(zp[4 * q + 3]), "v"(Bhi));
            }
            const float s0 = sne[k + 0], s1 = sne[k + 1];
            float t00 = __builtin_fmaf(-2.0f, a0.x, tnz0 + s0);
            float t01 = __builtin_fmaf(-2.0f, a1.x, tnz0 + s1);
            float t10 = __builtin_fmaf(-2.0f, a0.y, tnz1 + s0);
            float t11 = __builtin_fmaf(-2.0f, a1.y, tnz1 + s1);
            u64 p;
            p = ((u64)__float_as_uint(t00) << 32) | (u64)(kbase + k + 0); if (p < best0) best0 = p;
            p = ((u64)__float_as_uint(t01) << 32) | (u64)(kbase + k + 1); if (p < best0) best0 = p;
            p = ((u64)__float_as_uint(t10) << 32) | (u64)(kbase + k + 0); if (p < best1) best1 = p;
            p = ((u64)__float_as_uint(t11) << 32) | (u64)(kbase + k + 1); if (p < best1) best1 = p;
        }
        __syncthreads();
    }
    part[(size_t)slice * N_TOK + token0] = best0;
    part[(size_t)slice * N_TOK + token1] = best1;
}

// ---------------------------------------------------------------------------
// Kernel C: combine nslice slice-partials (u64 min keeps first-index
// tie-break), write idx as float, histogram, gather z_q, write
// z_q_st = z + (z_q - z) exactly as the reference, accumulate sum((z_q-z)^2).
// ---------------------------------------------------------------------------
__global__ __launch_bounds__(256) void reduce_gather_kernel(
    const float* __restrict__ z, const float* __restrict__ cb,
    const u64* __restrict__ part, int* __restrict__ hist,
    float* __restrict__ lossAcc, float* __restrict__ out, int nslice) {
    const int t = blockIdx.x * 256 + threadIdx.x;
    u64 best = part[t];
    for (int s = 1; s < nslice; ++s) {
        u64 p = part[(size_t)s * N_TOK + t];
        if (p < best) best = p;
    }
    const int idx = (int)(best & 0xFFFFFFFFull);
    out[IDX_OFF + t] = (float)idx;
    atomicAdd(&hist[idx], 1);

    const float4* ev = (const float4*)(cb + (size_t)idx * EDIM);
    const float4* zv = (const float4*)(z + (size_t)t * EDIM);
    float* o = out + ZQ_OFF + (size_t)t * EDIM;  // out+1: 4B-aligned -> scalar stores
    float acc = 0.0f;
#pragma unroll
    for (int j = 0; j < 16; ++j) {
        float4 e = ev[j], zz = zv[j];
        float d;
        d = e.x - zz.x; o[4 * j + 0] = zz.x + d; acc = __builtin_fmaf(d, d, acc);
        d = e.y - zz.y; o[4 * j + 1] = zz.y + d; acc = __builtin_fmaf(d, d, acc);
        d = e.z - zz.z; o[4 * j + 2] = zz.z + d; acc = __builtin_fmaf(d, d, acc);
        d = e.w - zz.w; o[4 * j + 3] = zz.w + d; acc = __builtin_fmaf(d, d, acc);
    }
    __shared__ float red[256];
    red[threadIdx.x] = acc;
    __syncthreads();
    for (int s = 128; s > 0; s >>= 1) {
        if (threadIdx.x < s) red[threadIdx.x] += red[threadIdx.x + s];
        __syncthreads();
    }
    if (threadIdx.x == 0) atomicAdd(lossAcc, red[0]);
}

// ---------------------------------------------------------------------------
// Kernel D: perplexity from histogram + loss finalize.
// ---------------------------------------------------------------------------
__global__ __launch_bounds__(256) void finalize_kernel(
    const int* __restrict__ hist, const float* __restrict__ lossAcc,
    float* __restrict__ out) {
    __shared__ float red[256];
    float acc = 0.0f;
    for (int i = threadIdx.x; i < NE; i += 256) {
        float e = (float)hist[i] * (1.0f / 16384.0f);  // exact /n_tokens
        acc += e * logf(e + 1e-10f);
    }
    red[threadIdx.x] = acc;
    __syncthreads();
    for (int s = 128; s > 0; s >>= 1) {
        if (threadIdx.x < s) red[threadIdx.x] += red[threadIdx.x + s];
        __syncthreads();
    }
    if (threadIdx.x == 0) {
        out[PERP_OFF] = expf(-red[0]);
        float m = lossAcc[0] * (1.0f / 1048576.0f);    // exact /B*T*E
        out[0] = m + 0.25f * m;
    }
}

extern "C" void kernel_launch(void* const* d_in, const int* in_sizes, int n_in,
                              void* d_out, int out_size, void* d_ws, size_t ws_size,
                              hipStream_t stream) {
    const float* z  = (const float*)d_in[0];
    const float* cb = (const float*)d_in[1];
    float* out = (float*)d_out;

    // 32 slices (grid 1024 = 4 blocks/CU) if ws fits the 4 MB partial array,
    // else fall back to 16 slices (2 MB, known-good footprint).
    const size_t need32 = (size_t)32 * N_TOK * 8 + (size_t)(NE + 1) * 4;
    const int nslice = (ws_size >= need32) ? 32 : 16;
    const int csl = NE / nslice;

    char* ws = (char*)d_ws;
    u64*   part    = (u64*)ws;                                    // nslice*16384*8
    int*   hist    = (int*)(ws + (size_t)nslice * N_TOK * 8);     // 16 KB
    float* lossAcc = (float*)(hist + NE);                         // 4 B

    hipLaunchKernelGGL(dist_argmin_kernel,
                       dim3(N_TOK / (TPB * TOKPT), nslice), dim3(TPB), 0, stream,
                       z, cb, part, hist, lossAcc, csl);
    hipLaunchKernelGGL(reduce_gather_kernel, dim3(64), dim3(256), 0, stream,
                       z, cb, part, hist, lossAcc, out, nslice);
    hipLaunchKernelGGL(finalize_kernel, dim3(1), dim3(256), 0, stream,
                       hist, lossAcc, out);
}